// Round 6
// baseline (284.914 us; speedup 1.0000x reference)
//
#include <hip/hip_runtime.h>

typedef unsigned short u16;
typedef unsigned int u32;
typedef __bf16 bf16x8 __attribute__((ext_vector_type(8)));
typedef float f32x4 __attribute__((ext_vector_type(4)));

#define QSCALE 0.18033688011112f  // 0.125 * log2(e): folded into Q so p = 2^s

__device__ __forceinline__ u16 f2bf(float f) {
  u32 u = __builtin_bit_cast(u32, f);
  u += 0x7fffu + ((u >> 16) & 1u);   // RNE
  return (u16)(u >> 16);
}

__device__ __forceinline__ bf16x8 as_bf16x8(uint4 v) {
  return __builtin_bit_cast(bf16x8, v);
}

// async global->LDS, 16B per lane; LDS dest = wave-uniform base + lane*16
__device__ __forceinline__ void async16(const void* g, void* l) {
  __builtin_amdgcn_global_load_lds(
      (__attribute__((address_space(1))) void*)(g),
      (__attribute__((address_space(3))) void*)(l), 16, 0, 0);
}

// ---------------- merged prep: cast xq/xkv to bf16 + transpose-cast 3 weights
__global__ void prep_kernel(const float* __restrict__ xq, const float* __restrict__ xkv,
                            const float* __restrict__ Wq, const float* __restrict__ Wkv,
                            const float* __restrict__ Wo,
                            u16* __restrict__ Xq16, u16* __restrict__ Xkv16,
                            u16* __restrict__ WqT, u16* __restrict__ WkvT,
                            u16* __restrict__ WoT) {
  const int bid = blockIdx.x, tid = threadIdx.x;
  if (bid < 8192) {
    int i = bid * 256 + tid;
    const float* s; u16* d; int j;
    if (i < 1048576) { s = xq; d = Xq16; j = i; }
    else             { s = xkv; d = Xkv16; j = i - 1048576; }
    float4 v = ((const float4*)s)[j];
    ushort4 o;
    o.x = f2bf(v.x); o.y = f2bf(v.y); o.z = f2bf(v.z); o.w = f2bf(v.w);
    ((ushort4*)d)[j] = o;
    return;
  }
  const int b2 = bid - 8192;
  const int z = b2 >> 11, rem = b2 & 2047;
  const int by = rem >> 6, bx = rem & 63;
  const float* src; u16* dst; int Nd;
  if (z == 0)      { src = Wq;  dst = WqT;  Nd = 1024; }
  else if (z == 1) { src = Wkv; dst = WkvT; Nd = 2048; }
  else             { src = Wo;  dst = WoT;  Nd = 1024; }
  const int n0 = bx * 32, k0 = by * 32;
  if (n0 >= Nd) return;
  __shared__ float tile[32][33];
  const int tx = tid & 31, ty = tid >> 5;  // 32 x 8
#pragma unroll
  for (int j = 0; j < 4; ++j)
    tile[ty + 8 * j][tx] = src[(size_t)(k0 + ty + 8 * j) * Nd + n0 + tx];
  __syncthreads();
#pragma unroll
  for (int j = 0; j < 4; ++j)
    dst[(size_t)(n0 + ty + 8 * j) * 1024 + k0 + tx] = f2bf(tile[tx][ty + 8 * j]);
}

// ---------------------------------------------------------------- GEMM core
template <int MI>
static __device__ __forceinline__ void gemm_core(
    const u16* __restrict__ A, const u16* __restrict__ Bt, int m0,
    uint4* sA, uint4* sB, f32x4 (*acc)[4]) {
  const int tid = threadIdx.x;
  const int wv = tid >> 6, lane = tid & 63;
  const int quad = lane >> 4, l16 = lane & 15;
  const int wm = (wv >> 1) * (MI * 16), wn = (wv & 1) * 64;

  const int ib0 = wv * 128 + lane, ib1 = ib0 + 64;      // B: 512 slots
  const int br0 = ib0 >> 2, bc0 = (ib0 & 3) ^ ((br0 >> 1) & 3);
  const int br1 = ib1 >> 2, bc1 = (ib1 & 3) ^ ((br1 >> 1) & 3);
  const u16* gB0 = Bt + (size_t)br0 * 1024 + bc0 * 8;
  const u16* gB1 = Bt + (size_t)br1 * 1024 + bc1 * 8;

  const int ia0 = wv * (MI * 32) + lane;                // A: MI*128 slots
  const int ar0 = ia0 >> 2, ac0 = (ia0 & 3) ^ ((ar0 >> 1) & 3);
  const u16* gA0 = A + (size_t)(m0 + ar0) * 1024 + ac0 * 8;
  const int ia1 = ia0 + 64;
  const int ar1 = ia1 >> 2, ac1 = (ia1 & 3) ^ ((ar1 >> 1) & 3);
  const u16* gA1 = A + (size_t)(m0 + ar1) * 1024 + ac1 * 8;
  uint4* sAw = sA + wv * (MI * 32);
  uint4* sBw = sB + wv * 128;

  for (int k0 = 0; k0 < 1024; k0 += 32) {
    __syncthreads();
    async16(gA0 + k0, sAw);
    if (MI == 4) async16(gA1 + k0, sAw + 64);
    async16(gB0 + k0, sBw);
    async16(gB1 + k0, sBw + 64);
    __syncthreads();

    bf16x8 af[MI], bfr[4];
#pragma unroll
    for (int mi = 0; mi < MI; ++mi) {
      int r = wm + mi * 16 + l16;
      af[mi] = as_bf16x8(sA[r * 4 + (quad ^ ((r >> 1) & 3))]);
    }
#pragma unroll
    for (int ni = 0; ni < 4; ++ni) {
      int r = wn + ni * 16 + l16;
      bfr[ni] = as_bf16x8(sB[r * 4 + (quad ^ ((r >> 1) & 3))]);
    }
#pragma unroll
    for (int mi = 0; mi < MI; ++mi)
#pragma unroll
      for (int ni = 0; ni < 4; ++ni)
        acc[mi][ni] = __builtin_amdgcn_mfma_f32_16x16x32_bf16(
            af[mi], bfr[ni], acc[mi][ni], 0, 0, 0);
  }
}

// ------------------------------------- fused Q/K/V projection GEMM (N = 3072 virtual)
// Q, K -> plain [4096][1024] bf16 (coalesced); V -> [bh][dh][skv] packed ushort4.
__global__ __launch_bounds__(256, 2) void gemm_qkv(
    const u16* __restrict__ Xq, const u16* __restrict__ Xkv,
    const u16* __restrict__ WqT, const u16* __restrict__ WkvT,
    const float* __restrict__ bq, const float* __restrict__ bkv,
    u16* __restrict__ Qd, u16* __restrict__ Kd, u16* __restrict__ Vd) {
  __shared__ uint4 sA[512], sB[512];
  f32x4 acc[4][4] = {};
  const int n0 = blockIdx.x * 128, m0 = blockIdx.y * 128;
  const u16* A = (n0 < 1024) ? Xq : Xkv;
  const u16* Bt = (n0 < 1024) ? (WqT + (size_t)n0 * 1024)
                              : (WkvT + (size_t)(n0 - 1024) * 1024);
  const float* bias = (n0 < 1024) ? (bq + n0) : (bkv + (n0 - 1024));
  gemm_core<4>(A, Bt, m0, sA, sB, acc);

  const int tid = threadIdx.x, wv = tid >> 6, lane = tid & 63;
  const int quad = lane >> 4, l16 = lane & 15;
  const int wm = (wv >> 1) * 64, wn = (wv & 1) * 64;
  const int bb = m0 >> 11;
  const int gmb = m0 + wm + quad * 4;            // global row base (b*2048+ss)
  const int ssb = (m0 & 2047) + wm + quad * 4;   // seq base
#pragma unroll
  for (int ni = 0; ni < 4; ++ni) {
    const int gn = n0 + wn + ni * 16 + l16;      // virtual col; region uniform per ni
    const float bvn = bias[wn + ni * 16 + l16];
    if (gn < 1024) {                             // Q plain, pre-scaled
      u16* base = Qd + gn;
#pragma unroll
      for (int mi = 0; mi < 4; ++mi)
#pragma unroll
        for (int r = 0; r < 4; ++r)
          base[(size_t)(gmb + mi * 16 + r) * 1024] = f2bf((acc[mi][ni][r] + bvn) * QSCALE);
    } else if (gn < 2048) {                      // K plain
      u16* base = Kd + (gn - 1024);
#pragma unroll
      for (int mi = 0; mi < 4; ++mi)
#pragma unroll
        for (int r = 0; r < 4; ++r)
          base[(size_t)(gmb + mi * 16 + r) * 1024] = f2bf(acc[mi][ni][r] + bvn);
    } else {                                     // V^T: [bh][dh][skv], packed x4
      const int col = gn - 2048, hh = col >> 6, dh = col & 63;
      u16* base = Vd + ((size_t)(bb * 16 + hh) * 64 + dh) * 2048 + ssb;
#pragma unroll
      for (int mi = 0; mi < 4; ++mi) {
        ushort4 o;
        o.x = f2bf(acc[mi][ni][0] + bvn);
        o.y = f2bf(acc[mi][ni][1] + bvn);
        o.z = f2bf(acc[mi][ni][2] + bvn);
        o.w = f2bf(acc[mi][ni][3] + bvn);
        *(ushort4*)(base + mi * 16) = o;
      }
    }
  }
}

// ---------------------------------------------------------------- flash attention
// BARRIER-FREE, LDS-minimal design. R3's flash was ~97% LDS-pipe-bound (K/V frags
// read redundantly by all waves). Here every MFMA operand is k-contiguous in
// global memory (V was pre-transposed), so K/V fragments are loaded per-lane
// directly via global_load_dwordx4 (L1/L2-served; unique set is L3-resident).
// LDS holds only the wave-private P C->A-layout round-trip (double-buffered).
// Software pipeline: issue K(t) -> PV(t-1) (covers K latency) -> issue V(t) ->
// QK(t) -> exp2 -> sP. V(t) latency is covered by a full iteration.
__global__ __launch_bounds__(128, 2) void flash_attn(
    const u16* __restrict__ Q, const u16* __restrict__ K,
    const u16* __restrict__ V, u16* __restrict__ O) {
  __shared__ __align__(16) u16 sP[2][64][72];   // [buf][2 waves x 32 rows][pad 72]

  const int tid = threadIdx.x;
  const int wv = tid >> 6, lane = tid & 63;
  const int quad = lane >> 4, l16 = lane & 15;
  const int q0 = blockIdx.x * 64 + wv * 32;     // this wave's 32 q-rows
  const int h = blockIdx.y, b = blockIdx.z;

  const u16* Qb = Q + ((size_t)(b * 2048 + q0)) * 1024 + h * 64;
  // per-lane K base: row kv_local = 4*l16 (+ni), col = h*64 + quad*8 (+half*32)
  const u16* Kb = K + ((size_t)b * 2048 + 4 * l16) * 1024 + h * 64 + quad * 8;
  // per-lane V^T base: row dh = l16 (+16*ni), col kv = quad*8 (+half*32)
  const u16* Vb = V + ((size_t)(b * 16 + h) * 64 + l16) * 2048 + quad * 8;

  // Q frags resident all kernel (A-layout: m=l16, k=quad*8+j)
  bf16x8 qf[2][2];
#pragma unroll
  for (int rb = 0; rb < 2; ++rb) {
    const uint4* qp = (const uint4*)(Qb + (size_t)(rb * 16 + l16) * 1024);
    qf[rb][0] = as_bf16x8(qp[quad]);
    qf[rb][1] = as_bf16x8(qp[4 + quad]);
  }

  f32x4 oacc[2][4] = {};
  f32x4 lsum[2] = {};
  const uint4 ones4 = {0x3F803F80u, 0x3F803F80u, 0x3F803F80u, 0x3F803F80u};
  const bf16x8 ones = as_bf16x8(ones4);

  bf16x8 kreg[2][4], vreg[2][4];

  auto loadK = [&](int t) {                    // K[kv0+4*l16+ni][dh half]
    const u16* kp = Kb + (size_t)t * 65536;    // 64 rows x 1024
#pragma unroll
    for (int ni = 0; ni < 4; ++ni) {
      kreg[0][ni] = as_bf16x8(*(const uint4*)(kp + ni * 1024));
      kreg[1][ni] = as_bf16x8(*(const uint4*)(kp + ni * 1024 + 32));
    }
  };
  auto loadV = [&](int t) {                    // V^T[dh=16*ni+l16][kv half]
    const u16* vp = Vb + t * 64;
#pragma unroll
    for (int ni = 0; ni < 4; ++ni) {
      vreg[0][ni] = as_bf16x8(*(const uint4*)(vp + ni * 32768));
      vreg[1][ni] = as_bf16x8(*(const uint4*)(vp + ni * 32768 + 32));
    }
  };
  auto qk_exp = [&](int buf) {
#pragma unroll
    for (int rb = 0; rb < 2; ++rb) {
      f32x4 s4[4];
#pragma unroll
      for (int ni = 0; ni < 4; ++ni) {         // tile ni covers kv = 4*l16+ni
        f32x4 a = {0.f, 0.f, 0.f, 0.f};
        a = __builtin_amdgcn_mfma_f32_16x16x32_bf16(qf[rb][0], kreg[0][ni], a, 0, 0, 0);
        a = __builtin_amdgcn_mfma_f32_16x16x32_bf16(qf[rb][1], kreg[1][ni], a, 0, 0, 0);
        s4[ni] = a;
      }
#pragma unroll
      for (int r = 0; r < 4; ++r) {            // p = 2^s; 4 contiguous kv -> b64
        u32 u0 = __builtin_bit_cast(u32, exp2f(s4[0][r])) + 0x8000u;
        u32 u1 = __builtin_bit_cast(u32, exp2f(s4[1][r])) + 0x8000u;
        u32 u2 = __builtin_bit_cast(u32, exp2f(s4[2][r])) + 0x8000u;
        u32 u3 = __builtin_bit_cast(u32, exp2f(s4[3][r])) + 0x8000u;
        uint2 pk;
        pk.x = (u0 >> 16) | (u1 & 0xFFFF0000u);
        pk.y = (u2 >> 16) | (u3 & 0xFFFF0000u);
        *(uint2*)&sP[buf][wv * 32 + rb * 16 + quad * 4 + r][l16 * 4] = pk;
      }
    }
  };
  auto pv = [&](int buf) {
#pragma unroll
    for (int rb = 0; rb < 2; ++rb) {
      bf16x8 pf0 = as_bf16x8(*(const uint4*)&sP[buf][wv * 32 + rb * 16 + l16][quad * 8]);
      bf16x8 pf1 = as_bf16x8(*(const uint4*)&sP[buf][wv * 32 + rb * 16 + l16][32 + quad * 8]);
      lsum[rb] = __builtin_amdgcn_mfma_f32_16x16x32_bf16(pf0, ones, lsum[rb], 0, 0, 0);
      lsum[rb] = __builtin_amdgcn_mfma_f32_16x16x32_bf16(pf1, ones, lsum[rb], 0, 0, 0);
#pragma unroll
      for (int ni = 0; ni < 4; ++ni) {
        oacc[rb][ni] = __builtin_amdgcn_mfma_f32_16x16x32_bf16(pf0, vreg[0][ni], oacc[rb][ni], 0, 0, 0);
        oacc[rb][ni] = __builtin_amdgcn_mfma_f32_16x16x32_bf16(pf1, vreg[1][ni], oacc[rb][ni], 0, 0, 0);
      }
    }
  };

  loadK(0);
  loadV(0);
  qk_exp(0);
  for (int t = 1; t < 32; ++t) {
    loadK(t);          // kregs free (QK(t-1) consumed them last iter)
    pv((t - 1) & 1);   // uses vreg(t-1) + sP(t-1); covers K(t) load latency
    loadV(t);          // vregs now free
    qk_exp(t & 1);     // waits on K(t) only (fine-grained vmcnt)
  }
  pv(1);               // tile 31

  // epilogue: O plain [4096][1024] bf16, normalized by MFMA row-sums
#pragma unroll
  for (int rb = 0; rb < 2; ++rb) {
    u16* Ob = O + ((size_t)(b * 2048 + q0 + rb * 16 + quad * 4)) * 1024 + h * 64;
#pragma unroll
    for (int r = 0; r < 4; ++r) {
      float rl = 1.0f / lsum[rb][r];
#pragma unroll
      for (int ni = 0; ni < 4; ++ni)
        Ob[(size_t)r * 1024 + ni * 16 + l16] = f2bf(oacc[rb][ni][r] * rl);
    }
  }
}

// ---------------------------------------------------------------- output projection
__global__ __launch_bounds__(256, 2) void gemm_out(
    const u16* __restrict__ A, const u16* __restrict__ Bt,
    const float* __restrict__ bias, float* __restrict__ C) {
  __shared__ uint4 sA[256], sB[512];
  f32x4 acc[2][4] = {};
  const int n0 = blockIdx.x * 128, m0 = blockIdx.y * 64;
  gemm_core<2>(A, Bt + (size_t)n0 * 1024, m0, sA, sB, acc);

  const int tid = threadIdx.x, wv = tid >> 6, lane = tid & 63;
  const int quad = lane >> 4, l16 = lane & 15;
  const int wm = (wv >> 1) * 32, wn = (wv & 1) * 64;
  float bv[4];
#pragma unroll
  for (int ni = 0; ni < 4; ++ni) bv[ni] = bias[n0 + wn + ni * 16 + l16];
#pragma unroll
  for (int mi = 0; mi < 2; ++mi)
#pragma unroll
    for (int ni = 0; ni < 4; ++ni)
#pragma unroll
      for (int r = 0; r < 4; ++r) {
        int gm = m0 + wm + mi * 16 + quad * 4 + r;
        int gn = n0 + wn + ni * 16 + l16;
        C[(size_t)gm * 1024 + gn] = acc[mi][ni][r] + bv[ni];
      }
}

extern "C" void kernel_launch(void* const* d_in, const int* in_sizes, int n_in,
                              void* d_out, int out_size, void* d_ws, size_t ws_size,
                              hipStream_t stream) {
  const float* xq  = (const float*)d_in[0];
  const float* xkv = (const float*)d_in[1];
  const float* Wq  = (const float*)d_in[2];
  const float* bq  = (const float*)d_in[3];
  const float* Wkv = (const float*)d_in[4];
  const float* bkv = (const float*)d_in[5];
  const float* Wo  = (const float*)d_in[6];
  const float* bo  = (const float*)d_in[7];
  float* out = (float*)d_out;

  char* p = (char*)d_ws;                       // 56 MiB total
  u16* Xq16  = (u16*)p; p += (size_t)8 << 20;  // [4096][1024] bf16
  u16* Xkv16 = (u16*)p; p += (size_t)8 << 20;
  u16* WqT   = (u16*)p; p += (size_t)2 << 20;  // [1024][1024]
  u16* WkvT  = (u16*)p; p += (size_t)4 << 20;  // [2048][1024]
  u16* WoT   = (u16*)p; p += (size_t)2 << 20;
  u16* Q16   = (u16*)p; p += (size_t)8 << 20;  // plain [4096][1024], pre-scaled
  u16* K16   = (u16*)p; p += (size_t)8 << 20;  // plain [4096][1024]
  u16* Vt16  = (u16*)p; p += (size_t)8 << 20;  // [bh][dh][skv]
  u16* O16   = (u16*)p; p += (size_t)8 << 20;  // plain [4096][1024]

  prep_kernel<<<14336, 256, 0, stream>>>(xq, xkv, Wq, Wkv, Wo,
                                         Xq16, Xkv16, WqT, WkvT, WoT);
  gemm_qkv<<<dim3(24, 32), 256, 0, stream>>>(Xq16, Xkv16, WqT, WkvT, bq, bkv,
                                             Q16, K16, Vt16);
  flash_attn<<<dim3(32, 16, 2), 128, 0, stream>>>(Q16, K16, Vt16, O16);
  gemm_out<<<dim3(8, 64), 256, 0, stream>>>(O16, WoT, bo, out);
}

// Round 7
// 223.107 us; speedup vs baseline: 1.2770x; 1.2770x over previous
//
#include <hip/hip_runtime.h>

typedef unsigned short u16;
typedef unsigned int u32;
typedef __bf16 bf16x8 __attribute__((ext_vector_type(8)));
typedef __bf16 bf16x2 __attribute__((ext_vector_type(2)));
typedef float f32x4 __attribute__((ext_vector_type(4)));

#define QSCALE 0.18033688011112f  // 0.125 * log2(e): folded into Q so p = 2^s

__device__ __forceinline__ u16 f2bf(float f) {
  u32 u = __builtin_bit_cast(u32, f);
  u += 0x7fffu + ((u >> 16) & 1u);   // RNE
  return (u16)(u >> 16);
}

// packed f32x2 -> bf16x2 (RNE), emits v_cvt_pk_bf16_f32 on gfx950
__device__ __forceinline__ u32 pkbf(float a, float b) {
  bf16x2 t = {(__bf16)a, (__bf16)b};
  return __builtin_bit_cast(u32, t);
}

__device__ __forceinline__ float bf2f(u16 x) {
  u32 u = (u32)x << 16;
  return __builtin_bit_cast(float, u);
}

__device__ __forceinline__ bf16x8 as_bf16x8(uint4 v) {
  return __builtin_bit_cast(bf16x8, v);
}

// async global->LDS, 16B per lane; LDS dest = wave-uniform base + lane*16
__device__ __forceinline__ void async16(const void* g, void* l) {
  __builtin_amdgcn_global_load_lds(
      (__attribute__((address_space(1))) void*)(g),
      (__attribute__((address_space(3))) void*)(l), 16, 0, 0);
}

// ---------------- merged prep: cast xq/xkv to bf16 + transpose-cast 3 weights
__global__ void prep_kernel(const float* __restrict__ xq, const float* __restrict__ xkv,
                            const float* __restrict__ Wq, const float* __restrict__ Wkv,
                            const float* __restrict__ Wo,
                            u16* __restrict__ Xq16, u16* __restrict__ Xkv16,
                            u16* __restrict__ WqT, u16* __restrict__ WkvT,
                            u16* __restrict__ WoT) {
  const int bid = blockIdx.x, tid = threadIdx.x;
  if (bid < 8192) {
    int i = bid * 256 + tid;
    const float* s; u16* d; int j;
    if (i < 1048576) { s = xq; d = Xq16; j = i; }
    else             { s = xkv; d = Xkv16; j = i - 1048576; }
    float4 v = ((const float4*)s)[j];
    ushort4 o;
    o.x = f2bf(v.x); o.y = f2bf(v.y); o.z = f2bf(v.z); o.w = f2bf(v.w);
    ((ushort4*)d)[j] = o;
    return;
  }
  const int b2 = bid - 8192;
  const int z = b2 >> 11, rem = b2 & 2047;
  const int by = rem >> 6, bx = rem & 63;
  const float* src; u16* dst; int Nd;
  if (z == 0)      { src = Wq;  dst = WqT;  Nd = 1024; }
  else if (z == 1) { src = Wkv; dst = WkvT; Nd = 2048; }
  else             { src = Wo;  dst = WoT;  Nd = 1024; }
  const int n0 = bx * 32, k0 = by * 32;
  if (n0 >= Nd) return;
  __shared__ float tile[32][33];
  const int tx = tid & 31, ty = tid >> 5;  // 32 x 8
#pragma unroll
  for (int j = 0; j < 4; ++j)
    tile[ty + 8 * j][tx] = src[(size_t)(k0 + ty + 8 * j) * Nd + n0 + tx];
  __syncthreads();
#pragma unroll
  for (int j = 0; j < 4; ++j)
    dst[(size_t)(n0 + ty + 8 * j) * 1024 + k0 + tx] = f2bf(tile[tx][ty + 8 * j]);
}

// ---------------------------------------------------------------- GEMM core
template <int MI>
static __device__ __forceinline__ void gemm_core(
    const u16* __restrict__ A, const u16* __restrict__ Bt, int m0,
    uint4* sA, uint4* sB, f32x4 (*acc)[4]) {
  const int tid = threadIdx.x;
  const int wv = tid >> 6, lane = tid & 63;
  const int quad = lane >> 4, l16 = lane & 15;
  const int wm = (wv >> 1) * (MI * 16), wn = (wv & 1) * 64;

  const int ib0 = wv * 128 + lane, ib1 = ib0 + 64;      // B: 512 slots
  const int br0 = ib0 >> 2, bc0 = (ib0 & 3) ^ ((br0 >> 1) & 3);
  const int br1 = ib1 >> 2, bc1 = (ib1 & 3) ^ ((br1 >> 1) & 3);
  const u16* gB0 = Bt + (size_t)br0 * 1024 + bc0 * 8;
  const u16* gB1 = Bt + (size_t)br1 * 1024 + bc1 * 8;

  const int ia0 = wv * (MI * 32) + lane;                // A: MI*128 slots
  const int ar0 = ia0 >> 2, ac0 = (ia0 & 3) ^ ((ar0 >> 1) & 3);
  const u16* gA0 = A + (size_t)(m0 + ar0) * 1024 + ac0 * 8;
  const int ia1 = ia0 + 64;
  const int ar1 = ia1 >> 2, ac1 = (ia1 & 3) ^ ((ar1 >> 1) & 3);
  const u16* gA1 = A + (size_t)(m0 + ar1) * 1024 + ac1 * 8;
  uint4* sAw = sA + wv * (MI * 32);
  uint4* sBw = sB + wv * 128;

  for (int k0 = 0; k0 < 1024; k0 += 32) {
    __syncthreads();
    async16(gA0 + k0, sAw);
    if (MI == 4) async16(gA1 + k0, sAw + 64);
    async16(gB0 + k0, sBw);
    async16(gB1 + k0, sBw + 64);
    __syncthreads();

    bf16x8 af[MI], bfr[4];
#pragma unroll
    for (int mi = 0; mi < MI; ++mi) {
      int r = wm + mi * 16 + l16;
      af[mi] = as_bf16x8(sA[r * 4 + (quad ^ ((r >> 1) & 3))]);
    }
#pragma unroll
    for (int ni = 0; ni < 4; ++ni) {
      int r = wn + ni * 16 + l16;
      bfr[ni] = as_bf16x8(sB[r * 4 + (quad ^ ((r >> 1) & 3))]);
    }
#pragma unroll
    for (int mi = 0; mi < MI; ++mi)
#pragma unroll
      for (int ni = 0; ni < 4; ++ni)
        acc[mi][ni] = __builtin_amdgcn_mfma_f32_16x16x32_bf16(
            af[mi], bfr[ni], acc[mi][ni], 0, 0, 0);
  }
}

// ------------------------------------- fused Q/K/V projection GEMM (N = 3072 virtual)
// Q, K -> plain [4096][1024] bf16 (coalesced); V -> [bh][dh][skv] packed ushort4.
__global__ __launch_bounds__(256, 3) void gemm_qkv(
    const u16* __restrict__ Xq, const u16* __restrict__ Xkv,
    const u16* __restrict__ WqT, const u16* __restrict__ WkvT,
    const float* __restrict__ bq, const float* __restrict__ bkv,
    u16* __restrict__ Qd, u16* __restrict__ Kd, u16* __restrict__ Vd) {
  __shared__ uint4 sA[512], sB[512];
  f32x4 acc[4][4] = {};
  const int n0 = blockIdx.x * 128, m0 = blockIdx.y * 128;
  const u16* A = (n0 < 1024) ? Xq : Xkv;
  const u16* Bt = (n0 < 1024) ? (WqT + (size_t)n0 * 1024)
                              : (WkvT + (size_t)(n0 - 1024) * 1024);
  const float* bias = (n0 < 1024) ? (bq + n0) : (bkv + (n0 - 1024));
  gemm_core<4>(A, Bt, m0, sA, sB, acc);

  const int tid = threadIdx.x, wv = tid >> 6, lane = tid & 63;
  const int quad = lane >> 4, l16 = lane & 15;
  const int wm = (wv >> 1) * 64, wn = (wv & 1) * 64;
  const int bb = m0 >> 11;
  const int gmb = m0 + wm + quad * 4;            // global row base (b*2048+ss)
  const int ssb = (m0 & 2047) + wm + quad * 4;   // seq base
#pragma unroll
  for (int ni = 0; ni < 4; ++ni) {
    const int gn = n0 + wn + ni * 16 + l16;      // virtual col; region uniform per ni
    const float bvn = bias[wn + ni * 16 + l16];
    if (gn < 1024) {                             // Q plain, pre-scaled
      u16* base = Qd + gn;
#pragma unroll
      for (int mi = 0; mi < 4; ++mi)
#pragma unroll
        for (int r = 0; r < 4; ++r)
          base[(size_t)(gmb + mi * 16 + r) * 1024] = f2bf((acc[mi][ni][r] + bvn) * QSCALE);
    } else if (gn < 2048) {                      // K plain
      u16* base = Kd + (gn - 1024);
#pragma unroll
      for (int mi = 0; mi < 4; ++mi)
#pragma unroll
        for (int r = 0; r < 4; ++r)
          base[(size_t)(gmb + mi * 16 + r) * 1024] = f2bf(acc[mi][ni][r] + bvn);
    } else {                                     // V^T: [bh][dh][skv], packed x4
      const int col = gn - 2048, hh = col >> 6, dh = col & 63;
      u16* base = Vd + ((size_t)(bb * 16 + hh) * 64 + dh) * 2048 + ssb;
#pragma unroll
      for (int mi = 0; mi < 4; ++mi) {
        ushort4 o;
        o.x = f2bf(acc[mi][ni][0] + bvn);
        o.y = f2bf(acc[mi][ni][1] + bvn);
        o.z = f2bf(acc[mi][ni][2] + bvn);
        o.w = f2bf(acc[mi][ni][3] + bvn);
        *(ushort4*)(base + mi * 16) = o;
      }
    }
  }
}

// ---------------------------------------------------------------- flash attention
// R3 core (256 thr, BQ=128, BKV=64, dbuf staging, ONE barrier/iter) with:
//  * rb-sequential sP -> LDS 41 KB -> 3 blocks/CU (123.6/160 KB, robust margin)
//  * clean kv-split x2 (blockIdx.z = b*2+split): partials are additive (no
//    max-subtraction), each split plain-stores bf16 sum(p*V) + fp32 sum(p);
//    NO atomics, NO memset (every element written exactly once).
//  * v_cvt_pk_bf16_f32 pack for P.
__global__ __launch_bounds__(256, 3) void flash_attn(
    const u16* __restrict__ Q, const u16* __restrict__ K,
    const u16* __restrict__ V, u16* __restrict__ Op,
    float* __restrict__ Lp) {
  __shared__ uint4 sK[2][512];              // 64 kv x 64 dh, x2 buffers
  __shared__ uint4 sV[2][512];              // 64 dh x 64 kv (V^T), x2
  __shared__ __align__(16) u16 sP[4][16][72];   // one rb at a time (wave-private)

  const int tid = threadIdx.x;
  const int wv = tid >> 6, lane = tid & 63;
  const int quad = lane >> 4, l16 = lane & 15;
  const int q0 = blockIdx.x * 128;
  const int h = blockIdx.y;
  const int bz = blockIdx.z >> 1, split = blockIdx.z & 1;
  const int kv0 = split * 1024;

  // Q,K plain [B*S][1024]; V^T [bh][dh][skv]
  const u16* Qb = Q + ((size_t)(bz * 2048 + q0)) * 1024 + h * 64;
  const u16* Kb = K + ((size_t)(bz * 2048 + kv0)) * 1024 + h * 64;
  const u16* Vb = V + ((size_t)(bz * 16 + h)) * 64 * 2048 + kv0;

  // Q frags resident all kernel (A-layout: m=l16, k=quad*8+j)
  bf16x8 qf[2][2];
#pragma unroll
  for (int rb = 0; rb < 2; ++rb) {
    const uint4* qp = (const uint4*)(Qb + (size_t)(wv * 32 + rb * 16 + l16) * 1024);
    qf[rb][0] = as_bf16x8(qp[quad]);
    qf[rb][1] = as_bf16x8(qp[4 + quad]);
  }

  f32x4 oacc[2][4] = {};
  f32x4 lsum[2] = {};
  const uint4 ones4 = {0x3F803F80u, 0x3F803F80u, 0x3F803F80u, 0x3F803F80u};
  const bf16x8 ones = as_bf16x8(ones4);

  const int i0 = wv * 128 + lane, i1 = i0 + 64;
  const int kr0 = i0 >> 3, kr1 = i1 >> 3;
  const int kck0 = (i0 & 7) ^ ((i0 >> 5) & 7);   // K swizzle: ^((row>>2)&7)
  const int kck1 = (i1 & 7) ^ ((i1 >> 5) & 7);
  const int vck0 = (i0 & 7) ^ (kr0 & 7);         // V swizzle: ^(row&7)
  const int vck1 = (i1 & 7) ^ (kr1 & 7);
  const u16* gK0 = Kb + (size_t)kr0 * 1024 + kck0 * 8;
  const u16* gK1 = Kb + (size_t)kr1 * 1024 + kck1 * 8;
  const u16* gV0 = Vb + (size_t)kr0 * 2048 + vck0 * 8;
  const u16* gV1 = Vb + (size_t)kr1 * 2048 + vck1 * 8;
  const int wo = wv * 128;

  // prologue: tile 0 -> buffer 0
  async16(gK0, &sK[0][wo]);
  async16(gK1, &sK[0][wo + 64]);
  async16(gV0, &sV[0][wo]);
  async16(gV1, &sV[0][wo + 64]);

  for (int t = 0; t < 16; ++t) {
    const int cur = t & 1;
    __syncthreads();   // drains loads for tile t (issued one iter ago)
    if (t < 15) {
      const int nxt = cur ^ 1;
      const size_t ko = (size_t)(t + 1) * 64 * 1024;   // 64 K rows (plain stride 1024)
      const int vo = (t + 1) * 64;                     // 64 kv cols
      async16(gK0 + ko, &sK[nxt][wo]);
      async16(gK1 + ko, &sK[nxt][wo + 64]);
      async16(gV0 + vo, &sV[nxt][wo]);
      async16(gV1 + vo, &sV[nxt][wo + 64]);
    }
    const uint4* K_ = sK[cur];
    const uint4* V_ = sV[cur];

    // K and V frags hoisted: read ONCE per iter, reused for both rb halves
    bf16x8 bK0[4], bK1[4], vf0[4], vf1[4];
#pragma unroll
    for (int ni = 0; ni < 4; ++ni) {
      int rr = l16 * 4 + ni;                     // interleaved kv = 4*l16+ni
      bK0[ni] = as_bf16x8(K_[rr * 8 + (quad ^ (l16 & 7))]);
      bK1[ni] = as_bf16x8(K_[rr * 8 + ((4 + quad) ^ (l16 & 7))]);
      int vv = ni * 16 + l16;
      vf0[ni] = as_bf16x8(V_[vv * 8 + (quad ^ (vv & 7))]);
      vf1[ni] = as_bf16x8(V_[vv * 8 + ((4 + quad) ^ (vv & 7))]);
    }

#pragma unroll
    for (int rb = 0; rb < 2; ++rb) {
      f32x4 s4[4];
#pragma unroll
      for (int ni = 0; ni < 4; ++ni) {
        f32x4 a = {0.f, 0.f, 0.f, 0.f};
        a = __builtin_amdgcn_mfma_f32_16x16x32_bf16(qf[rb][0], bK0[ni], a, 0, 0, 0);
        a = __builtin_amdgcn_mfma_f32_16x16x32_bf16(qf[rb][1], bK1[ni], a, 0, 0, 0);
        s4[ni] = a;
      }
      // p = 2^s; 4 contiguous kv per row -> v_cvt_pk + one b64 write
#pragma unroll
      for (int r = 0; r < 4; ++r) {
        uint2 pk;
        pk.x = pkbf(exp2f(s4[0][r]), exp2f(s4[1][r]));
        pk.y = pkbf(exp2f(s4[2][r]), exp2f(s4[3][r]));
        *(uint2*)&sP[wv][quad * 4 + r][l16 * 4] = pk;
      }
      // sP wave-private: lgkmcnt ordering suffices, no barrier
      bf16x8 pf0 = as_bf16x8(*(const uint4*)&sP[wv][l16][quad * 8]);
      bf16x8 pf1 = as_bf16x8(*(const uint4*)&sP[wv][l16][32 + quad * 8]);
      lsum[rb] = __builtin_amdgcn_mfma_f32_16x16x32_bf16(pf0, ones, lsum[rb], 0, 0, 0);
      lsum[rb] = __builtin_amdgcn_mfma_f32_16x16x32_bf16(pf1, ones, lsum[rb], 0, 0, 0);
#pragma unroll
      for (int ni = 0; ni < 4; ++ni) {
        oacc[rb][ni] = __builtin_amdgcn_mfma_f32_16x16x32_bf16(pf0, vf0[ni], oacc[rb][ni], 0, 0, 0);
        oacc[rb][ni] = __builtin_amdgcn_mfma_f32_16x16x32_bf16(pf1, vf1[ni], oacc[rb][ni], 0, 0, 0);
      }
    }
  }

  // epilogue: plain stores of this split's partials (bf16 numerator, fp32 sum)
#pragma unroll
  for (int rb = 0; rb < 2; ++rb) {
    const int row = bz * 2048 + q0 + wv * 32 + rb * 16 + quad * 4;
    u16* Ob = Op + ((size_t)split * 4096 + row) * 1024 + h * 64;
#pragma unroll
    for (int r = 0; r < 4; ++r)
#pragma unroll
      for (int ni = 0; ni < 4; ++ni)
        Ob[(size_t)r * 1024 + ni * 16 + l16] = f2bf(oacc[rb][ni][r]);
    if (l16 == 0)
#pragma unroll
      for (int r = 0; r < 4; ++r)
        Lp[((size_t)split * 4096 + row + r) * 16 + h] = lsum[rb][r];
  }
}

// --------------- combine: O16 = bf16((Op0+Op1) / (L0+L1)), one block per row
__global__ void combine_kernel(const u16* __restrict__ Op,
                               const float* __restrict__ Lp,
                               u16* __restrict__ O16) {
  const int row = blockIdx.x, t = threadIdx.x;   // 4096 x 256; cols 4t..4t+3
  const int h = t >> 4;
  const float rl = 1.0f / (Lp[(size_t)row * 16 + h] + Lp[(size_t)(4096 + row) * 16 + h]);
  ushort4 a = ((const ushort4*)(Op + (size_t)row * 1024))[t];
  ushort4 b = ((const ushort4*)(Op + (size_t)(4096 + row) * 1024))[t];
  ushort4 o;
  o.x = f2bf((bf2f(a.x) + bf2f(b.x)) * rl);
  o.y = f2bf((bf2f(a.y) + bf2f(b.y)) * rl);
  o.z = f2bf((bf2f(a.z) + bf2f(b.z)) * rl);
  o.w = f2bf((bf2f(a.w) + bf2f(b.w)) * rl);
  ((ushort4*)(O16 + (size_t)row * 1024))[t] = o;
}

// ---------------------------------------------------------------- output projection
__global__ __launch_bounds__(256, 2) void gemm_out(
    const u16* __restrict__ A, const u16* __restrict__ Bt,
    const float* __restrict__ bias, float* __restrict__ C) {
  __shared__ uint4 sA[256], sB[512];
  f32x4 acc[2][4] = {};
  const int n0 = blockIdx.x * 128, m0 = blockIdx.y * 64;
  gemm_core<2>(A, Bt + (size_t)n0 * 1024, m0, sA, sB, acc);

  const int tid = threadIdx.x, wv = tid >> 6, lane = tid & 63;
  const int quad = lane >> 4, l16 = lane & 15;
  const int wm = (wv >> 1) * 32, wn = (wv & 1) * 64;
  float bv[4];
#pragma unroll
  for (int ni = 0; ni < 4; ++ni) bv[ni] = bias[n0 + wn + ni * 16 + l16];
#pragma unroll
  for (int mi = 0; mi < 2; ++mi)
#pragma unroll
    for (int ni = 0; ni < 4; ++ni)
#pragma unroll
      for (int r = 0; r < 4; ++r) {
        int gm = m0 + wm + mi * 16 + quad * 4 + r;
        int gn = n0 + wn + ni * 16 + l16;
        C[(size_t)gm * 1024 + gn] = acc[mi][ni][r] + bv[ni];
      }
}

extern "C" void kernel_launch(void* const* d_in, const int* in_sizes, int n_in,
                              void* d_out, int out_size, void* d_ws, size_t ws_size,
                              hipStream_t stream) {
  const float* xq  = (const float*)d_in[0];
  const float* xkv = (const float*)d_in[1];
  const float* Wq  = (const float*)d_in[2];
  const float* bq  = (const float*)d_in[3];
  const float* Wkv = (const float*)d_in[4];
  const float* bkv = (const float*)d_in[5];
  const float* Wo  = (const float*)d_in[6];
  const float* bo  = (const float*)d_in[7];
  float* out = (float*)d_out;

  char* p = (char*)d_ws;                       // 56 MiB total
  u16* Xq16  = (u16*)p; p += (size_t)8 << 20;  // [4096][1024] bf16  \ Op (bf16 x2
  u16* Xkv16 = (u16*)p; p += (size_t)8 << 20;  //                    / splits) overlays
  u16* WqT   = (u16*)p; p += (size_t)2 << 20;  // [1024][1024]       | Lp overlays
  u16* WkvT  = (u16*)p; p += (size_t)4 << 20;  // [2048][1024]
  u16* WoT   = (u16*)p; p += (size_t)2 << 20;
  u16* Q16   = (u16*)p; p += (size_t)8 << 20;  // plain [4096][1024], pre-scaled
  u16* K16   = (u16*)p; p += (size_t)8 << 20;  // plain [4096][1024]
  u16* Vt16  = (u16*)p; p += (size_t)8 << 20;  // [bh][dh][skv]
  u16* O16   = (u16*)p; p += (size_t)8 << 20;  // plain [4096][1024]
  u16* Op    = Xq16;                           // [2][4096][1024] bf16 partial numerators
  float* Lp  = (float*)WqT;                    // [2][4096][16] fp32 partial sums

  prep_kernel<<<14336, 256, 0, stream>>>(xq, xkv, Wq, Wkv, Wo,
                                         Xq16, Xkv16, WqT, WkvT, WoT);
  gemm_qkv<<<dim3(24, 32), 256, 0, stream>>>(Xq16, Xkv16, WqT, WkvT, bq, bkv,
                                             Q16, K16, Vt16);
  // Xq16/Xkv16/WqT dead from here; overlaid by Op/Lp (plain stores, no init needed)
  flash_attn<<<dim3(16, 16, 4), 256, 0, stream>>>(Q16, K16, Vt16, Op, Lp);
  combine_kernel<<<4096, 256, 0, stream>>>(Op, Lp, O16);
  gemm_out<<<dim3(8, 64), 256, 0, stream>>>(O16, WoT, bo, out);
}

// Round 8
// 210.803 us; speedup vs baseline: 1.3516x; 1.0584x over previous
//
#include <hip/hip_runtime.h>

typedef unsigned short u16;
typedef unsigned int u32;
typedef __bf16 bf16x8 __attribute__((ext_vector_type(8)));
typedef __bf16 bf16x2 __attribute__((ext_vector_type(2)));
typedef float f32x4 __attribute__((ext_vector_type(4)));

#define QSCALE 0.18033688011112f  // 0.125 * log2(e): folded into Q so p = 2^s

__device__ __forceinline__ u16 f2bf(float f) {
  u32 u = __builtin_bit_cast(u32, f);
  u += 0x7fffu + ((u >> 16) & 1u);   // RNE
  return (u16)(u >> 16);
}

// packed f32x2 -> bf16x2 (RNE), emits v_cvt_pk_bf16_f32 on gfx950
__device__ __forceinline__ u32 pkbf(float a, float b) {
  bf16x2 t = {(__bf16)a, (__bf16)b};
  return __builtin_bit_cast(u32, t);
}

__device__ __forceinline__ bf16x8 as_bf16x8(uint4 v) {
  return __builtin_bit_cast(bf16x8, v);
}

// async global->LDS, 16B per lane; LDS dest = wave-uniform base + lane*16
__device__ __forceinline__ void async16(const void* g, void* l) {
  __builtin_amdgcn_global_load_lds(
      (__attribute__((address_space(1))) void*)(g),
      (__attribute__((address_space(3))) void*)(l), 16, 0, 0);
}

// ---------------- merged prep: cast xq/xkv to bf16 + transpose-cast 3 weights
__global__ void prep_kernel(const float* __restrict__ xq, const float* __restrict__ xkv,
                            const float* __restrict__ Wq, const float* __restrict__ Wkv,
                            const float* __restrict__ Wo,
                            u16* __restrict__ Xq16, u16* __restrict__ Xkv16,
                            u16* __restrict__ WqT, u16* __restrict__ WkvT,
                            u16* __restrict__ WoT) {
  const int bid = blockIdx.x, tid = threadIdx.x;
  if (bid < 8192) {
    int i = bid * 256 + tid;
    const float* s; u16* d; int j;
    if (i < 1048576) { s = xq; d = Xq16; j = i; }
    else             { s = xkv; d = Xkv16; j = i - 1048576; }
    float4 v = ((const float4*)s)[j];
    ushort4 o;
    o.x = f2bf(v.x); o.y = f2bf(v.y); o.z = f2bf(v.z); o.w = f2bf(v.w);
    ((ushort4*)d)[j] = o;
    return;
  }
  const int b2 = bid - 8192;
  const int z = b2 >> 11, rem = b2 & 2047;
  const int by = rem >> 6, bx = rem & 63;
  const float* src; u16* dst; int Nd;
  if (z == 0)      { src = Wq;  dst = WqT;  Nd = 1024; }
  else if (z == 1) { src = Wkv; dst = WkvT; Nd = 2048; }
  else             { src = Wo;  dst = WoT;  Nd = 1024; }
  const int n0 = bx * 32, k0 = by * 32;
  if (n0 >= Nd) return;
  __shared__ float tile[32][33];
  const int tx = tid & 31, ty = tid >> 5;  // 32 x 8
#pragma unroll
  for (int j = 0; j < 4; ++j)
    tile[ty + 8 * j][tx] = src[(size_t)(k0 + ty + 8 * j) * Nd + n0 + tx];
  __syncthreads();
#pragma unroll
  for (int j = 0; j < 4; ++j)
    dst[(size_t)(n0 + ty + 8 * j) * 1024 + k0 + tx] = f2bf(tile[tx][ty + 8 * j]);
}

// ---------------------------------------------------------------- GEMM core
template <int MI>
static __device__ __forceinline__ void gemm_core(
    const u16* __restrict__ A, const u16* __restrict__ Bt, int m0,
    uint4* sA, uint4* sB, f32x4 (*acc)[4]) {
  const int tid = threadIdx.x;
  const int wv = tid >> 6, lane = tid & 63;
  const int quad = lane >> 4, l16 = lane & 15;
  const int wm = (wv >> 1) * (MI * 16), wn = (wv & 1) * 64;

  const int ib0 = wv * 128 + lane, ib1 = ib0 + 64;      // B: 512 slots
  const int br0 = ib0 >> 2, bc0 = (ib0 & 3) ^ ((br0 >> 1) & 3);
  const int br1 = ib1 >> 2, bc1 = (ib1 & 3) ^ ((br1 >> 1) & 3);
  const u16* gB0 = Bt + (size_t)br0 * 1024 + bc0 * 8;
  const u16* gB1 = Bt + (size_t)br1 * 1024 + bc1 * 8;

  const int ia0 = wv * (MI * 32) + lane;                // A: MI*128 slots
  const int ar0 = ia0 >> 2, ac0 = (ia0 & 3) ^ ((ar0 >> 1) & 3);
  const u16* gA0 = A + (size_t)(m0 + ar0) * 1024 + ac0 * 8;
  const int ia1 = ia0 + 64;
  const int ar1 = ia1 >> 2, ac1 = (ia1 & 3) ^ ((ar1 >> 1) & 3);
  const u16* gA1 = A + (size_t)(m0 + ar1) * 1024 + ac1 * 8;
  uint4* sAw = sA + wv * (MI * 32);
  uint4* sBw = sB + wv * 128;

  for (int k0 = 0; k0 < 1024; k0 += 32) {
    __syncthreads();
    async16(gA0 + k0, sAw);
    if (MI == 4) async16(gA1 + k0, sAw + 64);
    async16(gB0 + k0, sBw);
    async16(gB1 + k0, sBw + 64);
    __syncthreads();

    bf16x8 af[MI], bfr[4];
#pragma unroll
    for (int mi = 0; mi < MI; ++mi) {
      int r = wm + mi * 16 + l16;
      af[mi] = as_bf16x8(sA[r * 4 + (quad ^ ((r >> 1) & 3))]);
    }
#pragma unroll
    for (int ni = 0; ni < 4; ++ni) {
      int r = wn + ni * 16 + l16;
      bfr[ni] = as_bf16x8(sB[r * 4 + (quad ^ ((r >> 1) & 3))]);
    }
#pragma unroll
    for (int mi = 0; mi < MI; ++mi)
#pragma unroll
      for (int ni = 0; ni < 4; ++ni)
        acc[mi][ni] = __builtin_amdgcn_mfma_f32_16x16x32_bf16(
            af[mi], bfr[ni], acc[mi][ni], 0, 0, 0);
  }
}

// ------------------------------------- fused Q/K/V projection GEMM (N = 3072 virtual)
// Q, K -> plain [4096][1024] bf16 (coalesced); V -> [bh][dh][skv] packed ushort4.
__global__ __launch_bounds__(256, 3) void gemm_qkv(
    const u16* __restrict__ Xq, const u16* __restrict__ Xkv,
    const u16* __restrict__ WqT, const u16* __restrict__ WkvT,
    const float* __restrict__ bq, const float* __restrict__ bkv,
    u16* __restrict__ Qd, u16* __restrict__ Kd, u16* __restrict__ Vd) {
  __shared__ uint4 sA[512], sB[512];
  f32x4 acc[4][4] = {};
  const int n0 = blockIdx.x * 128, m0 = blockIdx.y * 128;
  const u16* A = (n0 < 1024) ? Xq : Xkv;
  const u16* Bt = (n0 < 1024) ? (WqT + (size_t)n0 * 1024)
                              : (WkvT + (size_t)(n0 - 1024) * 1024);
  const float* bias = (n0 < 1024) ? (bq + n0) : (bkv + (n0 - 1024));
  gemm_core<4>(A, Bt, m0, sA, sB, acc);

  const int tid = threadIdx.x, wv = tid >> 6, lane = tid & 63;
  const int quad = lane >> 4, l16 = lane & 15;
  const int wm = (wv >> 1) * 64, wn = (wv & 1) * 64;
  const int bb = m0 >> 11;
  const int gmb = m0 + wm + quad * 4;            // global row base (b*2048+ss)
  const int ssb = (m0 & 2047) + wm + quad * 4;   // seq base
#pragma unroll
  for (int ni = 0; ni < 4; ++ni) {
    const int gn = n0 + wn + ni * 16 + l16;      // virtual col; region uniform per ni
    const float bvn = bias[wn + ni * 16 + l16];
    if (gn < 1024) {                             // Q plain, pre-scaled
      u16* base = Qd + gn;
#pragma unroll
      for (int mi = 0; mi < 4; ++mi)
#pragma unroll
        for (int r = 0; r < 4; ++r)
          base[(size_t)(gmb + mi * 16 + r) * 1024] = f2bf((acc[mi][ni][r] + bvn) * QSCALE);
    } else if (gn < 2048) {                      // K plain
      u16* base = Kd + (gn - 1024);
#pragma unroll
      for (int mi = 0; mi < 4; ++mi)
#pragma unroll
        for (int r = 0; r < 4; ++r)
          base[(size_t)(gmb + mi * 16 + r) * 1024] = f2bf(acc[mi][ni][r] + bvn);
    } else {                                     // V^T: [bh][dh][skv], packed x4
      const int col = gn - 2048, hh = col >> 6, dh = col & 63;
      u16* base = Vd + ((size_t)(bb * 16 + hh) * 64 + dh) * 2048 + ssb;
#pragma unroll
      for (int mi = 0; mi < 4; ++mi) {
        ushort4 o;
        o.x = f2bf(acc[mi][ni][0] + bvn);
        o.y = f2bf(acc[mi][ni][1] + bvn);
        o.z = f2bf(acc[mi][ni][2] + bvn);
        o.w = f2bf(acc[mi][ni][3] + bvn);
        *(ushort4*)(base + mi * 16) = o;
      }
    }
  }
}

// ---------------------------------------------------------------- flash attention
// R3 core (256 thr, BQ=128, BKV=64, dbuf staging, ONE barrier/iter), no kv-split,
// direct normalized O16 output. NEW: XCD-aware flat grid — bid = hb + 32*q_blk,
// so the 16 q-blocks sharing one (h,b)'s 512 KB K/V slice land on the SAME XCD
// (linear%8 round-robin heuristic) and hit its private L2 instead of the long
// TCC-miss path. Per XCD: 4 groups x 512 KB = 2 MB < 4 MB L2; 64 blocks/XCD
// matches 2-blocks/CU co-residency exactly.
__global__ __launch_bounds__(256, 2) void flash_attn(
    const u16* __restrict__ Q, const u16* __restrict__ K,
    const u16* __restrict__ V, u16* __restrict__ O) {
  __shared__ uint4 sK[2][512];              // 64 kv x 64 dh, x2 buffers
  __shared__ uint4 sV[2][512];              // 64 dh x 64 kv (V^T), x2
  __shared__ __align__(16) u16 sP[4][32][72];

  const int tid = threadIdx.x;
  const int wv = tid >> 6, lane = tid & 63;
  const int quad = lane >> 4, l16 = lane & 15;
  const int hb = blockIdx.x & 31;           // fast dim: (h, b) -> fixes XCD
  const int q0 = (blockIdx.x >> 5) * 128;   // slow dim: q-block
  const int h = hb & 15, bz = hb >> 4;

  // Q,K plain [B*S][1024]; V^T [bh][dh][skv]
  const u16* Qb = Q + ((size_t)(bz * 2048 + q0)) * 1024 + h * 64;
  const u16* Kb = K + ((size_t)(bz * 2048)) * 1024 + h * 64;
  const u16* Vb = V + ((size_t)(bz * 16 + h)) * 64 * 2048;

  // Q frags resident all kernel (A-layout: m=l16, k=quad*8+j)
  bf16x8 qf[2][2];
#pragma unroll
  for (int rb = 0; rb < 2; ++rb) {
    const uint4* qp = (const uint4*)(Qb + (size_t)(wv * 32 + rb * 16 + l16) * 1024);
    qf[rb][0] = as_bf16x8(qp[quad]);
    qf[rb][1] = as_bf16x8(qp[4 + quad]);
  }

  f32x4 oacc[2][4] = {};
  f32x4 lsum[2] = {};
  const uint4 ones4 = {0x3F803F80u, 0x3F803F80u, 0x3F803F80u, 0x3F803F80u};
  const bf16x8 ones = as_bf16x8(ones4);

  const int i0 = wv * 128 + lane, i1 = i0 + 64;
  const int kr0 = i0 >> 3, kr1 = i1 >> 3;
  const int kck0 = (i0 & 7) ^ ((i0 >> 5) & 7);   // K swizzle: ^((row>>2)&7)
  const int kck1 = (i1 & 7) ^ ((i1 >> 5) & 7);
  const int vck0 = (i0 & 7) ^ (kr0 & 7);         // V swizzle: ^(row&7)
  const int vck1 = (i1 & 7) ^ (kr1 & 7);
  const u16* gK0 = Kb + (size_t)kr0 * 1024 + kck0 * 8;
  const u16* gK1 = Kb + (size_t)kr1 * 1024 + kck1 * 8;
  const u16* gV0 = Vb + (size_t)kr0 * 2048 + vck0 * 8;
  const u16* gV1 = Vb + (size_t)kr1 * 2048 + vck1 * 8;
  const int wo = wv * 128;

  // prologue: tile 0 -> buffer 0
  async16(gK0, &sK[0][wo]);
  async16(gK1, &sK[0][wo + 64]);
  async16(gV0, &sV[0][wo]);
  async16(gV1, &sV[0][wo + 64]);

  for (int t = 0; t < 32; ++t) {
    const int cur = t & 1;
    __syncthreads();   // drains loads for tile t (issued one iter ago)
    if (t < 31) {
      const int nxt = cur ^ 1;
      const size_t ko = (size_t)(t + 1) * 64 * 1024;   // 64 K rows (plain stride 1024)
      const int vo = (t + 1) * 64;                     // 64 kv cols
      async16(gK0 + ko, &sK[nxt][wo]);
      async16(gK1 + ko, &sK[nxt][wo + 64]);
      async16(gV0 + vo, &sV[nxt][wo]);
      async16(gV1 + vo, &sV[nxt][wo + 64]);
    }
    const uint4* K_ = sK[cur];
    const uint4* V_ = sV[cur];

    // K and V frags hoisted: read ONCE per iter, reused for both rb halves
    bf16x8 bK0[4], bK1[4], vf0[4], vf1[4];
#pragma unroll
    for (int ni = 0; ni < 4; ++ni) {
      int rr = l16 * 4 + ni;                     // interleaved kv = 4*l16+ni
      bK0[ni] = as_bf16x8(K_[rr * 8 + (quad ^ (l16 & 7))]);
      bK1[ni] = as_bf16x8(K_[rr * 8 + ((4 + quad) ^ (l16 & 7))]);
      int vv = ni * 16 + l16;
      vf0[ni] = as_bf16x8(V_[vv * 8 + (quad ^ (vv & 7))]);
      vf1[ni] = as_bf16x8(V_[vv * 8 + ((4 + quad) ^ (vv & 7))]);
    }

    // QK + exp for BOTH rb halves first (writes overlap), then PV for both
#pragma unroll
    for (int rb = 0; rb < 2; ++rb) {
      f32x4 s4[4];
#pragma unroll
      for (int ni = 0; ni < 4; ++ni) {
        f32x4 a = {0.f, 0.f, 0.f, 0.f};
        a = __builtin_amdgcn_mfma_f32_16x16x32_bf16(qf[rb][0], bK0[ni], a, 0, 0, 0);
        a = __builtin_amdgcn_mfma_f32_16x16x32_bf16(qf[rb][1], bK1[ni], a, 0, 0, 0);
        s4[ni] = a;
      }
#pragma unroll
      for (int r = 0; r < 4; ++r) {              // p = 2^s; v_cvt_pk + b64 write
        uint2 pk;
        pk.x = pkbf(exp2f(s4[0][r]), exp2f(s4[1][r]));
        pk.y = pkbf(exp2f(s4[2][r]), exp2f(s4[3][r]));
        *(uint2*)&sP[wv][rb * 16 + quad * 4 + r][l16 * 4] = pk;
      }
    }
    // sP wave-private: lgkmcnt ordering suffices, no barrier
#pragma unroll
    for (int rb = 0; rb < 2; ++rb) {
      bf16x8 pf0 = as_bf16x8(*(const uint4*)&sP[wv][rb * 16 + l16][quad * 8]);
      bf16x8 pf1 = as_bf16x8(*(const uint4*)&sP[wv][rb * 16 + l16][32 + quad * 8]);
      lsum[rb] = __builtin_amdgcn_mfma_f32_16x16x32_bf16(pf0, ones, lsum[rb], 0, 0, 0);
      lsum[rb] = __builtin_amdgcn_mfma_f32_16x16x32_bf16(pf1, ones, lsum[rb], 0, 0, 0);
#pragma unroll
      for (int ni = 0; ni < 4; ++ni) {
        oacc[rb][ni] = __builtin_amdgcn_mfma_f32_16x16x32_bf16(pf0, vf0[ni], oacc[rb][ni], 0, 0, 0);
        oacc[rb][ni] = __builtin_amdgcn_mfma_f32_16x16x32_bf16(pf1, vf1[ni], oacc[rb][ni], 0, 0, 0);
      }
    }
  }

  // epilogue: O16 plain [4096][1024] bf16, normalized by MFMA row-sums
#pragma unroll
  for (int rb = 0; rb < 2; ++rb) {
    u16* Ob = O + ((size_t)(bz * 2048 + q0 + wv * 32 + rb * 16 + quad * 4)) * 1024
                + h * 64;
#pragma unroll
    for (int r = 0; r < 4; ++r) {
      float rl = 1.0f / lsum[rb][r];
#pragma unroll
      for (int ni = 0; ni < 4; ++ni)
        Ob[(size_t)r * 1024 + ni * 16 + l16] = f2bf(oacc[rb][ni][r] * rl);
    }
  }
}

// ---------------------------------------------------------------- output projection
__global__ __launch_bounds__(256, 2) void gemm_out(
    const u16* __restrict__ A, const u16* __restrict__ Bt,
    const float* __restrict__ bias, float* __restrict__ C) {
  __shared__ uint4 sA[256], sB[512];
  f32x4 acc[2][4] = {};
  const int n0 = blockIdx.x * 128, m0 = blockIdx.y * 64;
  gemm_core<2>(A, Bt + (size_t)n0 * 1024, m0, sA, sB, acc);

  const int tid = threadIdx.x, wv = tid >> 6, lane = tid & 63;
  const int quad = lane >> 4, l16 = lane & 15;
  const int wm = (wv >> 1) * 32, wn = (wv & 1) * 64;
  float bv[4];
#pragma unroll
  for (int ni = 0; ni < 4; ++ni) bv[ni] = bias[n0 + wn + ni * 16 + l16];
#pragma unroll
  for (int mi = 0; mi < 2; ++mi)
#pragma unroll
    for (int ni = 0; ni < 4; ++ni)
#pragma unroll
      for (int r = 0; r < 4; ++r) {
        int gm = m0 + wm + mi * 16 + quad * 4 + r;
        int gn = n0 + wn + ni * 16 + l16;
        C[(size_t)gm * 1024 + gn] = acc[mi][ni][r] + bv[ni];
      }
}

extern "C" void kernel_launch(void* const* d_in, const int* in_sizes, int n_in,
                              void* d_out, int out_size, void* d_ws, size_t ws_size,
                              hipStream_t stream) {
  const float* xq  = (const float*)d_in[0];
  const float* xkv = (const float*)d_in[1];
  const float* Wq  = (const float*)d_in[2];
  const float* bq  = (const float*)d_in[3];
  const float* Wkv = (const float*)d_in[4];
  const float* bkv = (const float*)d_in[5];
  const float* Wo  = (const float*)d_in[6];
  const float* bo  = (const float*)d_in[7];
  float* out = (float*)d_out;

  char* p = (char*)d_ws;                       // 56 MiB total
  u16* Xq16  = (u16*)p; p += (size_t)8 << 20;  // [4096][1024] bf16
  u16* Xkv16 = (u16*)p; p += (size_t)8 << 20;
  u16* WqT   = (u16*)p; p += (size_t)2 << 20;  // [1024][1024]
  u16* WkvT  = (u16*)p; p += (size_t)4 << 20;  // [2048][1024]
  u16* WoT   = (u16*)p; p += (size_t)2 << 20;
  u16* Q16   = (u16*)p; p += (size_t)8 << 20;  // plain [4096][1024], pre-scaled
  u16* K16   = (u16*)p; p += (size_t)8 << 20;  // plain [4096][1024]
  u16* Vt16  = (u16*)p; p += (size_t)8 << 20;  // [bh][dh][skv]
  u16* O16   = (u16*)p; p += (size_t)8 << 20;  // plain [4096][1024]

  prep_kernel<<<14336, 256, 0, stream>>>(xq, xkv, Wq, Wkv, Wo,
                                         Xq16, Xkv16, WqT, WkvT, WoT);
  gemm_qkv<<<dim3(24, 32), 256, 0, stream>>>(Xq16, Xkv16, WqT, WkvT, bq, bkv,
                                             Q16, K16, Vt16);
  flash_attn<<<512, 256, 0, stream>>>(Q16, K16, Vt16, O16);
  gemm_out<<<dim3(8, 64), 256, 0, stream>>>(O16, WoT, bo, out);
}